// Round 18
// baseline (207.569 us; speedup 1.0000x reference)
//
#include <hip/hip_runtime.h>
#include <hip/hip_bf16.h>
#include <cstdint>

typedef __attribute__((ext_vector_type(8))) __bf16 bf16v8;
typedef __attribute__((ext_vector_type(4))) float f32x4;
typedef __attribute__((ext_vector_type(4))) unsigned short ushort4v;
typedef __attribute__((ext_vector_type(8))) unsigned short ushort8v;

#define BB 8
#define NN 2048
#define DD 768

__device__ __forceinline__ float b2f(unsigned short u) {
  union { unsigned int i; float f; } c; c.i = ((unsigned int)u) << 16; return c.f;
}
__device__ __forceinline__ unsigned short f2b(float f) {
  union { float f; unsigned int i; } c; c.f = f;
  unsigned int u = c.i;
  return (unsigned short)((u + 0x7fffu + ((u >> 16) & 1u)) >> 16);
}

// ---------------- prep: LayerNorm ∪ Wconvert ∪ mask_scan (block-partitioned) ----------------
__global__ __launch_bounds__(256) void prep(
    const float* __restrict__ x, const float* __restrict__ gamma, const float* __restrict__ beta,
    unsigned short* __restrict__ xb,
    const float* __restrict__ Wq, const float* __restrict__ Wk, const float* __restrict__ Wv,
    unsigned short* __restrict__ Wcat,
    const int* __restrict__ mask, int* __restrict__ kidx, int* __restrict__ ncnt) {
  __shared__ float red[2][4];
  __shared__ int wsum[4];
  const int bid = blockIdx.x;
  const int t = threadIdx.x;

  if (bid < BB * NN) {
    // ---- LayerNorm row ----
    const int row = bid;
    const float* xr = x + (size_t)row * DD;
    float a0 = xr[t], a1 = xr[t + 256], a2 = xr[t + 512];
    float s = a0 + a1 + a2;
    float q = a0 * a0 + a1 * a1 + a2 * a2;
    for (int o = 32; o > 0; o >>= 1) { s += __shfl_xor(s, o); q += __shfl_xor(q, o); }
    int w = t >> 6, lane = t & 63;
    if (lane == 0) { red[0][w] = s; red[1][w] = q; }
    __syncthreads();
    s = red[0][0] + red[0][1] + red[0][2] + red[0][3];
    q = red[1][0] + red[1][1] + red[1][2] + red[1][3];
    float mean = s * (1.0f / DD);
    float var = q * (1.0f / DD) - mean * mean;
    float inv = rsqrtf(var + 1e-5f);
    unsigned short* o0 = xb + (size_t)row * DD;
    o0[t]       = f2b((a0 - mean) * inv * gamma[t]       + beta[t]);
    o0[t + 256] = f2b((a1 - mean) * inv * gamma[t + 256] + beta[t + 256]);
    o0[t + 512] = f2b((a2 - mean) * inv * gamma[t + 512] + beta[t + 512]);
  } else if (bid < BB * NN + 6912) {
    // ---- weight concat/convert (scale folded into Wq) ----
    const int i = (bid - BB * NN) * 256 + t;
    const int dd = DD * DD;
    if (i < 3 * dd) {
      float v;
      if (i < dd)           v = Wq[i] * 0.03608439182435161f;   // 1/sqrt(768)
      else if (i < 2 * dd)  v = Wk[i - dd];
      else                  v = Wv[i - 2 * dd];
      Wcat[i] = f2b(v);
    }
  } else {
    // ---- mask prefix scan: kidx / ncnt (kidx pre-zeroed: pads map to row 0) ----
    const int b = bid - (BB * NN + 6912);
    const int* mr = mask + b * NN;
#pragma unroll
    for (int j = 0; j < 8; ++j) kidx[b * NN + t * 8 + j] = 0;
    int v[8]; int s = 0;
#pragma unroll
    for (int j = 0; j < 8; ++j) { v[j] = (mr[t * 8 + j] == 0) ? 1 : 0; s += v[j]; }
    int lane = t & 63, w = t >> 6;
    int xp = s;
    for (int o = 1; o < 64; o <<= 1) { int y = __shfl_up(xp, o); if (lane >= o) xp += y; }
    if (lane == 63) wsum[w] = xp;
    __syncthreads();
    int base = 0;
#pragma unroll
    for (int i = 0; i < 4; ++i) if (i < w) base += wsum[i];
    int run = base + xp - s;
#pragma unroll
    for (int j = 0; j < 8; ++j) { if (v[j]) kidx[b * NN + run] = t * 8 + j; run += v[j]; }
    if (t == 255) ncnt[b] = base + xp;
  }
}

// ---------------- async global->LDS (16B per lane, wave-uniform LDS base) ----------------
__device__ __forceinline__ void gload_lds16(const void* g, void* l) {
  __builtin_amdgcn_global_load_lds(
      (const __attribute__((address_space(1))) void*)g,
      (__attribute__((address_space(3))) void*)(unsigned)(uintptr_t)l,
      16, 0, 0);
}

// LDS geometry (elements): buffer b at b*32768.
//   slot A-ks at  buf + ks*8192          (256 rows x 32 cols, 64B rows)
//   slot B-ks at  buf + 16384 + ks*8192
#define RDA(i0, ks, B)                                                                   \
  _Pragma("unroll")                                                                      \
  for (int i_ = 0; i_ < 4; ++i_)                                                         \
    aq[i_] = *(const bf16v8*)&smem[(B) + (ks) * 8192 + arow0 + ((i0) + i_) * 512 + kg8];
#define RDB(ks, B)                                                                       \
  _Pragma("unroll")                                                                      \
  for (int j_ = 0; j_ < NJ; ++j_)                                                        \
    bq[j_] = *(const bf16v8*)&smem[(B) + 16384 + (ks) * 8192 + brow0 + j_ * 512 + kg8];
#define MFQ(i0)                                                                          \
  _Pragma("unroll")                                                                      \
  for (int i_ = 0; i_ < 4; ++i_) {                                                       \
    _Pragma("unroll")                                                                    \
    for (int j_ = 0; j_ < NJ; ++j_)                                                      \
      acc[(i0) + i_][j_] = __builtin_amdgcn_mfma_f32_16x16x32_bf16(                      \
          aq[i_], bq[j_], acc[(i0) + i_][j_], 0, 0, 0);                                  \
  }
#define BARF asm volatile("s_barrier" ::: "memory")
#define VMC6 asm volatile("s_waitcnt vmcnt(6)" ::: "memory")
#define VMC3 asm volatile("s_waitcnt vmcnt(3)" ::: "memory")
#define VMC0 asm volatile("s_waitcnt vmcnt(0)" ::: "memory")
#define P1   __builtin_amdgcn_s_setprio(1)
#define P0   __builtin_amdgcn_s_setprio(0)

// r6 per-tile schedule (256-row tiles):
#define TILEK(KT, CURB, NXTB)                                                            \
  do {                                                                                   \
    RDA(0, 0, CURB); RDB(0, CURB);                                                       \
    if ((KT) + 1 < NT) stgA((KT) + 1, 1, (NXTB));                                        \
    BARF; P1; MFQ(0); P0; BARF;                                                          \
    RDA(4, 0, CURB);                                                                     \
    if ((KT) + 1 < NT) stgB((KT) + 1, 1, (NXTB));                                        \
    BARF; P1; MFQ(4); P0;                                                                \
    VMC6; BARF;                                                                          \
    RDA(0, 1, CURB); RDB(1, CURB);                                                       \
    if ((KT) + 2 < NT) stgA((KT) + 2, 0, (CURB));                                        \
    BARF; P1; MFQ(0); P0; BARF;                                                          \
    RDA(4, 1, CURB);                                                                     \
    if ((KT) + 2 < NT) stgB((KT) + 2, 0, (CURB));                                        \
    BARF; P1; MFQ(4); P0;                                                                \
    if ((KT) < NT - 2) { VMC6; } else { VMC0; }                                          \
    BARF;                                                                                \
  } while (0)

// ---- context GEMM (r6 structure), C = A * B^T, f32 store, runtime NT = 2*ceil(nc/128) ----
template <int NJ>
__global__ __launch_bounds__(512, 2) void gemmCtx(
    const unsigned short* __restrict__ A, const unsigned short* __restrict__ Bm,
    float* __restrict__ Cf, int lda, int ldb,
    long aStride, long bStride, long cStride,
    const int* __restrict__ ncnt) {
  extern __shared__ unsigned short smem[];      // 65536 elems = 131072 B
  const int BN = NJ * 64;

  const int t = threadIdx.x;
  int bx = blockIdx.x, by = blockIdx.y, bz = blockIdx.z;
  {  // bijective XCD swizzle (grid %8==0)
    const int gx = gridDim.x, gy = gridDim.y;
    const int nwg = gx * gy * (int)gridDim.z;
    int id = bx + gx * (by + gy * bz);
    int sw = (id & 7) * (nwg >> 3) + (id >> 3);
    bx = sw % gx; int r2 = sw / gx;
    by = r2 % gy; bz = r2 / gy;
  }
  const int n0 = bx * BN, m0 = by * 256;
  const int NT = ((ncnt[bz] + 127) >> 7) << 1;

  const unsigned short* Ab = A + (size_t)bz * aStride;
  const unsigned short* Bb = Bm + (size_t)bz * bStride;

  const int lane = t & 63;
  const int w = t >> 6;
  const int wm = w >> 2, wn = w & 3;
  const int frow = lane & 15;
  const int kg8 = (lane >> 4) * 8;
  const int arow0 = (wm * 128 + frow) * 32;
  const int brow0 = (wn * (NJ * 16) + frow) * 32;

  const int srow = t >> 2;
  const int scol8 = (t & 3) * 8;
  const unsigned short* Asrc = Ab + (size_t)(m0 + srow) * lda + scol8;
  const unsigned short* Bsrc = Bb + (size_t)(n0 + srow) * ldb + scol8;
  const int sdst = w * 512;

  auto stgA = [&](int kt, int ks, int bufb) {
    const unsigned short* s = Asrc + kt * 64 + ks * 32;
    gload_lds16(s, &smem[bufb + ks * 8192 + sdst]);
    gload_lds16(s + (size_t)128 * lda, &smem[bufb + ks * 8192 + 4096 + sdst]);
  };
  auto stgB = [&](int kt, int ks, int bufb) {
    const unsigned short* s = Bsrc + kt * 64 + ks * 32;
    gload_lds16(s, &smem[bufb + 16384 + ks * 8192 + sdst]);
    gload_lds16(s + (size_t)128 * ldb, &smem[bufb + 16384 + ks * 8192 + 4096 + sdst]);
  };

  f32x4 acc[8][NJ] = {};
  bf16v8 aq[4], bq[NJ];

  stgA(0, 0, 0);     stgB(0, 0, 0);
  stgA(0, 1, 0);     stgB(0, 1, 0);
  stgA(1, 0, 32768); stgB(1, 0, 32768);
  asm volatile("s_waitcnt vmcnt(8)" ::: "memory");
  BARF;

  for (int ktp = 0; ktp < NT; ktp += 2) {
    TILEK(ktp, 0, 32768);
    TILEK(ktp + 1, 32768, 0);
  }

  const int r0 = (lane >> 4) * 4;
  const int c0 = lane & 15;
  const int mrowB = m0 + wm * 128 + r0;
  const int ncolB = n0 + wn * (NJ * 16) + c0;
  float* dst = Cf + (size_t)bz * cStride;
#pragma unroll
  for (int i = 0; i < 8; ++i)
#pragma unroll
    for (int j = 0; j < NJ; ++j)
#pragma unroll
      for (int r = 0; r < 4; ++r)
        dst[(size_t)(mrowB + i * 16 + r) * DD + (ncolB + j * 16)] = acc[i][j][r];
}

// ---- Merged Q + K/V projection, NJ=4, dense item pool, 2-pass coverage ----
// item < 192:  Q (64 m x 3 n): Q = Xb * Wcat[0:768]^T   (A contiguous)
// item >= 192: KV (GT x 6 n):  [Kc|Vtc] = gather(Xb,kidx) * Wcat[768:2304]^T
//   A staged with per-lane kidx indirection (independent base per 128-row half — r12 rule).
//   Pad rows map to kidx=0 (duplicate row 0): garbage lands only in Kc[nc..r256) rows /
//   Vtc[nc..r128) cols, both provably dead downstream (softmax zeroes P there).
template <int NJ>
__global__ __launch_bounds__(512, 2) void gemmQKV(
    const unsigned short* __restrict__ Xb, const unsigned short* __restrict__ Wcat,
    unsigned short* __restrict__ Qb, unsigned short* __restrict__ Kc,
    unsigned short* __restrict__ Vtc,
    const int* __restrict__ kidx, const int* __restrict__ ncnt) {
  extern __shared__ unsigned short smem[];      // 131072 B
  constexpr int NT = 12;

  const int t = threadIdx.x;
  const int bid = (int)blockIdx.x;
  const int lid = (bid & 7) * 64 + (bid >> 3);   // XCD chunking (512 grid)

  const int lane = t & 63;
  const int w = t >> 6;
  const int wm = w >> 2, wn = w & 3;
  const int frow = lane & 15;
  const int kg8 = (lane >> 4) * 8;
  const int arow0 = (wm * 128 + frow) * 32;
  const int brow0 = (wn * (NJ * 16) + frow) * 32;
  const int srow = t >> 2;
  const int scol8 = (t & 3) * 8;
  const int sdst = w * 512;
  const int r0 = (lane >> 4) * 4;
  const int c0 = lane & 15;

  int offv[9]; offv[0] = 0;
#pragma unroll
  for (int i = 0; i < 8; ++i) offv[i + 1] = offv[i] + ((ncnt[i] + 255) & ~255);
  const int GT = offv[8] >> 8;
  const int nItems = 192 + GT * 6;

  f32x4 acc[8][NJ];
  bf16v8 aq[4], bq[NJ];

#pragma unroll 1
  for (int pass = 0; pass < 2; ++pass) {
    const int item = lid + pass * 512;
    if (item >= nItems) break;
    const bool isQ = item < 192;
    int m0 = 0, ncolQ = 0, b = 0, cbase0 = 0, ni = 0;
    const unsigned short *Asrc0, *Asrc1, *Bsrc;
    if (isQ) {
      m0 = (item / 3) * 256;
      ncolQ = (item % 3) * 256;
      Asrc0 = Xb + (size_t)(m0 + srow) * DD + scol8;
      Asrc1 = Asrc0 + (size_t)128 * DD;
      Bsrc  = Wcat + (size_t)(ncolQ + srow) * DD + scol8;
    } else {
      const int kid = item - 192;
      const int gt = kid / 6; ni = kid % 6;
#pragma unroll
      for (int i = 1; i < 8; ++i) if (offv[i] <= gt * 256) b = i;
      cbase0 = gt * 256 - offv[b];
      // independent per-half indirection (pads -> kidx 0, finite dead-region garbage)
      Asrc0 = Xb + ((size_t)b * NN + kidx[b * NN + cbase0 + srow]) * DD + scol8;
      Asrc1 = Xb + ((size_t)b * NN + kidx[b * NN + cbase0 + 128 + srow]) * DD + scol8;
      Bsrc  = Wcat + (size_t)(768 + ni * 256 + srow) * DD + scol8;
    }

    auto stgA = [&](int kt, int ks, int bufb) {
      gload_lds16(Asrc0 + kt * 64 + ks * 32, &smem[bufb + ks * 8192 + sdst]);
      gload_lds16(Asrc1 + kt * 64 + ks * 32, &smem[bufb + ks * 8192 + 4096 + sdst]);
    };
    auto stgB = [&](int kt, int ks, int bufb) {
      const unsigned short* s = Bsrc + kt * 64 + ks * 32;
      gload_lds16(s, &smem[bufb + 16384 + ks * 8192 + sdst]);
      gload_lds16(s + (size_t)128 * DD, &smem[bufb + 16384 + ks * 8192 + 4096 + sdst]);
    };

#pragma unroll
    for (int i = 0; i < 8; ++i)
#pragma unroll
      for (int j = 0; j < NJ; ++j) acc[i][j] = f32x4{0.f, 0.f, 0.f, 0.f};

    // prologue: vmcnt(8) also drains the previous pass's epilogue stores
    stgA(0, 0, 0);     stgB(0, 0, 0);
    stgA(0, 1, 0);     stgB(0, 1, 0);
    stgA(1, 0, 32768); stgB(1, 0, 32768);
    asm volatile("s_waitcnt vmcnt(8)" ::: "memory");
    BARF;

    for (int ktp = 0; ktp < NT; ktp += 2) {
      TILEK(ktp, 0, 32768);
      TILEK(ktp + 1, 32768, 0);
    }

    if (isQ) {
      const int mrowB = m0 + wm * 128 + r0;
      const int ncolB = ncolQ + wn * (NJ * 16) + c0;
#pragma unroll
      for (int i = 0; i < 8; ++i)
#pragma unroll
        for (int j = 0; j < NJ; ++j)
#pragma unroll
          for (int r = 0; r < 4; ++r)
            Qb[(size_t)(mrowB + i * 16 + r) * DD + (ncolB + j * 16)] = f2b(acc[i][j][r]);
    } else {
      const int rowL = wm * 128 + r0;
      const int ncolL = ni * 256 + wn * (NJ * 16) + c0;
      const int cbase = cbase0 + rowL;
      if (ni < 3) {   // K region: dense compacted rows, ld=768
        unsigned short* dst = Kc + (size_t)b * NN * DD;
#pragma unroll
        for (int i = 0; i < 8; ++i)
#pragma unroll
          for (int j = 0; j < NJ; ++j)
#pragma unroll
            for (int r = 0; r < 4; ++r)
              dst[(size_t)(cbase + i * 16 + r) * DD + (ncolL + j * 16)] = f2b(acc[i][j][r]);
      } else {        // V region (ncolL >= 768): transposed, dense compacted cols
#pragma unroll
        for (int i = 0; i < 8; ++i) {
#pragma unroll
          for (int j = 0; j < NJ; ++j) {
            const int e = ncolL + j * 16 - 768;
            ushort4v pk;
#pragma unroll
            for (int r = 0; r < 4; ++r) pk[r] = f2b(acc[i][j][r]);
            *(ushort4v*)&Vtc[((size_t)b * DD + e) * NN + cbase + i * 16] = pk;
          }
        }
      }
    }
  }
}

// ---- Persistent scores GEMM, 128x256 items: S[b][m][c] = Q[b][m] . Kc[b][c] ----
// Block takes item pair (2*lid, 2*lid+1): same n-tile (n-major) -> shared Kc B-panel (L2-hot
// on the second job). XCD chunking on lid. Monotonic item order keeps early-exit correct.
__global__ __launch_bounds__(512, 2) void gemm1P(
    const unsigned short* __restrict__ Qa, const unsigned short* __restrict__ Kn,
    unsigned short* __restrict__ So, const int* __restrict__ ncnt) {
  extern __shared__ unsigned short smem[];      // 49152 elems = 98304 B
  constexpr int NT = 12;

  const int t = threadIdx.x;
  const int bid = (int)blockIdx.x;
  const int lid = (bid & 7) * 32 + (bid >> 3);
  const int lane = t & 63;
  const int w = t >> 6;
  const int wm = w >> 2, wn = w & 3;
  const int frow = lane & 15;
  const int kg8 = (lane >> 4) * 8;
  const int arow0 = (wm * 64 + frow) * 32;
  const int brow0 = (wn * 64 + frow) * 32;
  const int srow = t >> 2;
  const int scol8 = (t & 3) * 8;
  const int sdst = w * 512;
  const int r0 = (lane >> 4) * 4;
  const int c0 = lane & 15;

  int nbv[8];
#pragma unroll
  for (int b_ = 0; b_ < 8; ++b_) nbv[b_] = (ncnt[b_] + 255) >> 8;

  f32x4 acc[4][4];
  bf16v8 aq[4], bq[4];

#pragma unroll 1
  for (int it = 0; it < 4; ++it) {
    int rem = lid * 2 + (it & 1) + (it >> 1) * 512;   // 2lid, 2lid+1, 2lid+512, 2lid+513
    int b = 0;
#pragma unroll 1
    for (; b < 8; ++b) { int c = nbv[b] * 16; if (rem < c) break; rem -= c; }
    if (b >= 8) break;
    const int ni = rem >> 4, mi = rem & 15;
    const int m0 = mi * 128, n0 = ni * 256;

    const unsigned short* Asrc = Qa + ((size_t)b * NN + m0 + srow) * DD + scol8;
    const unsigned short* Bsrc = Kn + ((size_t)b * NN + n0 + srow) * DD + scol8;

    auto stgA = [&](int kt, int ks, int bufb) {
      gload_lds16(Asrc + kt * 64 + ks * 32, &smem[bufb + ks * 4096 + sdst]);
    };
    auto stgB = [&](int kt, int ks, int bufb) {
      const unsigned short* s = Bsrc + kt * 64 + ks * 32;
      gload_lds16(s, &smem[bufb + 8192 + ks * 8192 + sdst]);
      gload_lds16(s + (size_t)128 * DD, &smem[bufb + 8192 + ks * 8192 + 4096 + sdst]);
    };

#pragma unroll
    for (int i = 0; i < 4; ++i)
#pragma unroll
      for (int j = 0; j < 4; ++j) acc[i][j] = f32x4{0.f, 0.f, 0.f, 0.f};

    stgA(0, 0, 0);     stgB(0, 0, 0);
    stgA(0, 1, 0);     stgB(0, 1, 0);
    stgA(1, 0, 24576); stgB(1, 0, 24576);
    VMC3;
    BARF;

#pragma unroll 1
    for (int kt = 0; kt < NT; ++kt) {
      const int cur = (kt & 1) ? 24576 : 0;
      const int nxt = cur ^ 24576;
#pragma unroll
      for (int i_ = 0; i_ < 4; ++i_)
        aq[i_] = *(const bf16v8*)&smem[cur + arow0 + i_ * 512 + kg8];
#pragma unroll
      for (int j_ = 0; j_ < 4; ++j_)
        bq[j_] = *(const bf16v8*)&smem[cur + 8192 + brow0 + j_ * 512 + kg8];
      if (kt + 1 < NT) { stgA(kt + 1, 1, nxt); stgB(kt + 1, 1, nxt); }
      BARF; P1;
#pragma unroll
      for (int i_ = 0; i_ < 4; ++i_)
#pragma unroll
        for (int j_ = 0; j_ < 4; ++j_)
          acc[i_][j_] = __builtin_amdgcn_mfma_f32_16x16x32_bf16(aq[i_], bq[j_], acc[i_][j_], 0, 0, 0);
      P0; BARF;
#pragma unroll
      for (int i_ = 0; i_ < 4; ++i_)
        aq[i_] = *(const bf16v8*)&smem[cur + 4096 + arow0 + i_ * 512 + kg8];
#pragma unroll
      for (int j_ = 0; j_ < 4; ++j_)
        bq[j_] = *(const bf16v8*)&smem[cur + 16384 + brow0 + j_ * 512 + kg8];
      if (kt + 2 < NT) { stgA(kt + 2, 0, cur); stgB(kt + 2, 0, cur); }
      BARF; P1;
#pragma unroll
      for (int i_ = 0; i_ < 4; ++i_)
#pragma unroll
        for (int j_ = 0; j_ < 4; ++j_)
          acc[i_][j_] = __builtin_amdgcn_mfma_f32_16x16x32_bf16(aq[i_], bq[j_], acc[i_][j_], 0, 0, 0);
      P0;
      if (kt < NT - 2) { VMC3; } else { VMC0; }
      BARF;
    }

    unsigned short* dst = So + (size_t)b * NN * NN;
    const int mrowB = m0 + wm * 64 + r0;
    const int ncolB = n0 + wn * 64 + c0;
#pragma unroll
    for (int i = 0; i < 4; ++i)
#pragma unroll
      for (int j = 0; j < 4; ++j)
#pragma unroll
        for (int r = 0; r < 4; ++r)
          dst[(size_t)(mrowB + i * 16 + r) * NN + (ncolB + j * 16)] = f2b(acc[i][j][r]);
  }
}

// ---------------- compacted softmax: cols [0,nc) valid, zero-fill [nc,r128), skip rest ----------------
__global__ __launch_bounds__(256) void softmax_c(unsigned short* __restrict__ S,
                                                 const int* __restrict__ ncnt) {
  int row = blockIdx.x;            // 0..16383
  int bb = row >> 11;
  const int nc = ncnt[bb];
  const int p128 = (nc + 127) & ~127;
  unsigned short* sr = S + (size_t)row * NN;
  int t = threadIdx.x;
  const int cbase = t * 8;

  float v[8];
  const bool anyload = cbase < nc;
  ushort8v pk;
  if (anyload) pk = *(const ushort8v*)&sr[cbase];
  float mx = -1e30f;
#pragma unroll
  for (int j = 0; j < 8; ++j) {
    v[j] = anyload ? b2f(pk[j]) : 0.f;
    if (cbase + j < nc) mx = fmaxf(mx, v[j]);
  }
  for (int o = 32; o > 0; o >>= 1) mx = fmaxf(mx, __shfl_xor(mx, o));
  __shared__ float redm[4], reds[4];
  int w = t >> 6, lane = t & 63;
  if (lane == 0) redm[w] = mx;
  __syncthreads();
  mx = fmaxf(fmaxf(redm[0], redm[1]), fmaxf(redm[2], redm[3]));

  float e[8];
  float sum = 0.f;
#pragma unroll
  for (int j = 0; j < 8; ++j) {
    e[j] = (cbase + j < nc) ? __expf(v[j] - mx) : 0.f;
    sum += e[j];
  }
  for (int o = 32; o > 0; o >>= 1) sum += __shfl_xor(sum, o);
  if (lane == 0) reds[w] = sum;
  __syncthreads();
  sum = reds[0] + reds[1] + reds[2] + reds[3];
  float inv = 1.0f / sum;

  if (cbase < p128) {
    ushort8v op;
#pragma unroll
    for (int j = 0; j < 8; ++j) op[j] = f2b(e[j] * inv);
    *(ushort8v*)&sr[cbase] = op;
  }
}

extern "C" void kernel_launch(void* const* d_in, const int* in_sizes, int n_in,
                              void* d_out, int out_size, void* d_ws, size_t ws_size,
                              hipStream_t stream) {
  const float* features = (const float*)d_in[0];
  const int* mask       = (const int*)d_in[1];
  const float* Wq       = (const float*)d_in[2];
  const float* Wk       = (const float*)d_in[3];
  const float* Wv       = (const float*)d_in[4];
  const float* gamma    = (const float*)d_in[5];
  const float* beta     = (const float*)d_in[6];
  float* out = (float*)d_out;

  char* ws = (char*)d_ws;
  size_t off = 0;
  auto alloc = [&](size_t bytes) {
    char* p = ws + off;
    off += (bytes + 255) & ~(size_t)255;
    return p;
  };
  unsigned short* Wcat = (unsigned short*)alloc((size_t)(2304 + 64) * DD * 2);
  unsigned short* Qb   = (unsigned short*)alloc((size_t)BB * NN * DD * 2);
  unsigned short* Kc   = (unsigned short*)alloc((size_t)BB * NN * DD * 2);   // compacted K rows
  unsigned short* Vtc  = (unsigned short*)alloc(((size_t)BB * DD + 64) * NN * 2);  // compacted Vt cols
  int* kidx = (int*)alloc((size_t)BB * NN * 4);
  int* ncnt = (int*)alloc(64 * 4);
  // S (67 MB): Xb aliases its first 25 MB (dead before gemm1P writes S).
  char* last = alloc((size_t)BB * NN * NN * 2);
  unsigned short* Sb = (unsigned short*)last;
  unsigned short* Xb = (unsigned short*)last;

  (void)hipFuncSetAttribute(reinterpret_cast<const void*>(&gemmQKV<4>),
                            hipFuncAttributeMaxDynamicSharedMemorySize, 131072);
  (void)hipFuncSetAttribute(reinterpret_cast<const void*>(&gemm1P),
                            hipFuncAttributeMaxDynamicSharedMemorySize, 98304);
  (void)hipFuncSetAttribute(reinterpret_cast<const void*>(&gemmCtx<3>),
                            hipFuncAttributeMaxDynamicSharedMemorySize, 131072);

  // 1) prep: LN ∪ Wconvert ∪ mask_scan
  prep<<<BB * NN + 6912 + BB, 256, 0, stream>>>(
      features, gamma, beta, Xb, Wq, Wk, Wv, Wcat, mask, kidx, ncnt);

  // 2) merged Q + K/V projection (KV stages A from Xb via kidx; no Xc materialization)
  gemmQKV<4><<<512, 512, 131072, stream>>>(Xb, Wcat, Qb, Kc, Vtc, kidx, ncnt);

  // 3) scores (dense compacted keys, paired items for B-panel L2 reuse)
  gemm1P<<<256, 512, 98304, stream>>>(Qb, Kc, Sb, ncnt);

  // 4) compacted softmax
  softmax_c<<<BB * NN, 256, 0, stream>>>(Sb, ncnt);

  // 5) context: per batch P[2048,r128] x Vtc[768,r128]^T -> f32 out
  gemmCtx<3><<<dim3(DD / 192, NN / 256, BB), 512, 131072, stream>>>(
      Sb, Vtc, out, NN, NN,
      (long)NN * NN, (long)DD * NN, (long)NN * DD, ncnt);
}

// Round 19
// 193.448 us; speedup vs baseline: 1.0730x; 1.0730x over previous
//
#include <hip/hip_runtime.h>
#include <hip/hip_bf16.h>
#include <cstdint>

typedef __attribute__((ext_vector_type(8))) __bf16 bf16v8;
typedef __attribute__((ext_vector_type(4))) float f32x4;
typedef __attribute__((ext_vector_type(4))) unsigned short ushort4v;
typedef __attribute__((ext_vector_type(8))) unsigned short ushort8v;

#define BB 8
#define NN 2048
#define DD 768

__device__ __forceinline__ float b2f(unsigned short u) {
  union { unsigned int i; float f; } c; c.i = ((unsigned int)u) << 16; return c.f;
}
__device__ __forceinline__ unsigned short f2b(float f) {
  union { float f; unsigned int i; } c; c.f = f;
  unsigned int u = c.i;
  return (unsigned short)((u + 0x7fffu + ((u >> 16) & 1u)) >> 16);
}

// ---------------- prep: LayerNorm ∪ Wconvert ∪ mask_scan (block-partitioned) ----------------
__global__ __launch_bounds__(256) void prep(
    const float* __restrict__ x, const float* __restrict__ gamma, const float* __restrict__ beta,
    unsigned short* __restrict__ xb,
    const float* __restrict__ Wq, const float* __restrict__ Wk, const float* __restrict__ Wv,
    unsigned short* __restrict__ Wcat,
    const int* __restrict__ mask, int* __restrict__ kidx, int* __restrict__ ncnt) {
  __shared__ float red[2][4];
  __shared__ int wsum[4];
  const int bid = blockIdx.x;
  const int t = threadIdx.x;

  if (bid < BB * NN) {
    // ---- LayerNorm row ----
    const int row = bid;
    const float* xr = x + (size_t)row * DD;
    float a0 = xr[t], a1 = xr[t + 256], a2 = xr[t + 512];
    float s = a0 + a1 + a2;
    float q = a0 * a0 + a1 * a1 + a2 * a2;
    for (int o = 32; o > 0; o >>= 1) { s += __shfl_xor(s, o); q += __shfl_xor(q, o); }
    int w = t >> 6, lane = t & 63;
    if (lane == 0) { red[0][w] = s; red[1][w] = q; }
    __syncthreads();
    s = red[0][0] + red[0][1] + red[0][2] + red[0][3];
    q = red[1][0] + red[1][1] + red[1][2] + red[1][3];
    float mean = s * (1.0f / DD);
    float var = q * (1.0f / DD) - mean * mean;
    float inv = rsqrtf(var + 1e-5f);
    unsigned short* o0 = xb + (size_t)row * DD;
    o0[t]       = f2b((a0 - mean) * inv * gamma[t]       + beta[t]);
    o0[t + 256] = f2b((a1 - mean) * inv * gamma[t + 256] + beta[t + 256]);
    o0[t + 512] = f2b((a2 - mean) * inv * gamma[t + 512] + beta[t + 512]);
  } else if (bid < BB * NN + 6912) {
    // ---- weight concat/convert (scale folded into Wq) ----
    const int i = (bid - BB * NN) * 256 + t;
    const int dd = DD * DD;
    if (i < 3 * dd) {
      float v;
      if (i < dd)           v = Wq[i] * 0.03608439182435161f;   // 1/sqrt(768)
      else if (i < 2 * dd)  v = Wk[i - dd];
      else                  v = Wv[i - 2 * dd];
      Wcat[i] = f2b(v);
    }
  } else {
    // ---- mask prefix scan: kidx / ncnt (kidx pre-zeroed: pads map to row 0) ----
    const int b = bid - (BB * NN + 6912);
    const int* mr = mask + b * NN;
#pragma unroll
    for (int j = 0; j < 8; ++j) kidx[b * NN + t * 8 + j] = 0;
    int v[8]; int s = 0;
#pragma unroll
    for (int j = 0; j < 8; ++j) { v[j] = (mr[t * 8 + j] == 0) ? 1 : 0; s += v[j]; }
    int lane = t & 63, w = t >> 6;
    int xp = s;
    for (int o = 1; o < 64; o <<= 1) { int y = __shfl_up(xp, o); if (lane >= o) xp += y; }
    if (lane == 63) wsum[w] = xp;
    __syncthreads();
    int base = 0;
#pragma unroll
    for (int i = 0; i < 4; ++i) if (i < w) base += wsum[i];
    int run = base + xp - s;
#pragma unroll
    for (int j = 0; j < 8; ++j) { if (v[j]) kidx[b * NN + run] = t * 8 + j; run += v[j]; }
    if (t == 255) ncnt[b] = base + xp;
  }
}

// ---------------- async global->LDS (16B per lane, wave-uniform LDS base) ----------------
__device__ __forceinline__ void gload_lds16(const void* g, void* l) {
  __builtin_amdgcn_global_load_lds(
      (const __attribute__((address_space(1))) void*)g,
      (__attribute__((address_space(3))) void*)(unsigned)(uintptr_t)l,
      16, 0, 0);
}

// LDS geometry (elements): buffer b at b*32768.
//   slot A-ks at  buf + ks*8192          (256 rows x 32 cols, 64B rows)
//   slot B-ks at  buf + 16384 + ks*8192
#define RDA(i0, ks, B)                                                                   \
  _Pragma("unroll")                                                                      \
  for (int i_ = 0; i_ < 4; ++i_)                                                         \
    aq[i_] = *(const bf16v8*)&smem[(B) + (ks) * 8192 + arow0 + ((i0) + i_) * 512 + kg8];
#define RDB(ks, B)                                                                       \
  _Pragma("unroll")                                                                      \
  for (int j_ = 0; j_ < NJ; ++j_)                                                        \
    bq[j_] = *(const bf16v8*)&smem[(B) + 16384 + (ks) * 8192 + brow0 + j_ * 512 + kg8];
#define MFQ(i0)                                                                          \
  _Pragma("unroll")                                                                      \
  for (int i_ = 0; i_ < 4; ++i_) {                                                       \
    _Pragma("unroll")                                                                    \
    for (int j_ = 0; j_ < NJ; ++j_)                                                      \
      acc[(i0) + i_][j_] = __builtin_amdgcn_mfma_f32_16x16x32_bf16(                      \
          aq[i_], bq[j_], acc[(i0) + i_][j_], 0, 0, 0);                                  \
  }
#define BARF asm volatile("s_barrier" ::: "memory")
#define VMC6 asm volatile("s_waitcnt vmcnt(6)" ::: "memory")
#define VMC3 asm volatile("s_waitcnt vmcnt(3)" ::: "memory")
#define VMC0 asm volatile("s_waitcnt vmcnt(0)" ::: "memory")
#define P1   __builtin_amdgcn_s_setprio(1)
#define P0   __builtin_amdgcn_s_setprio(0)

// r6 per-tile schedule (256-row tiles):
#define TILEK(KT, CURB, NXTB)                                                            \
  do {                                                                                   \
    RDA(0, 0, CURB); RDB(0, CURB);                                                       \
    if ((KT) + 1 < NT) stgA((KT) + 1, 1, (NXTB));                                        \
    BARF; P1; MFQ(0); P0; BARF;                                                          \
    RDA(4, 0, CURB);                                                                     \
    if ((KT) + 1 < NT) stgB((KT) + 1, 1, (NXTB));                                        \
    BARF; P1; MFQ(4); P0;                                                                \
    VMC6; BARF;                                                                          \
    RDA(0, 1, CURB); RDB(1, CURB);                                                       \
    if ((KT) + 2 < NT) stgA((KT) + 2, 0, (CURB));                                        \
    BARF; P1; MFQ(0); P0; BARF;                                                          \
    RDA(4, 1, CURB);                                                                     \
    if ((KT) + 2 < NT) stgB((KT) + 2, 0, (CURB));                                        \
    BARF; P1; MFQ(4); P0;                                                                \
    if ((KT) < NT - 2) { VMC6; } else { VMC0; }                                          \
    BARF;                                                                                \
  } while (0)

// ---- context GEMM (r6 structure), C = A * B^T, f32 store, runtime NT = 2*ceil(nc/128) ----
template <int NJ>
__global__ __launch_bounds__(512, 2) void gemmCtx(
    const unsigned short* __restrict__ A, const unsigned short* __restrict__ Bm,
    float* __restrict__ Cf, int lda, int ldb,
    long aStride, long bStride, long cStride,
    const int* __restrict__ ncnt) {
  extern __shared__ unsigned short smem[];      // 65536 elems = 131072 B
  const int BN = NJ * 64;

  const int t = threadIdx.x;
  int bx = blockIdx.x, by = blockIdx.y, bz = blockIdx.z;
  {  // bijective XCD swizzle (grid %8==0)
    const int gx = gridDim.x, gy = gridDim.y;
    const int nwg = gx * gy * (int)gridDim.z;
    int id = bx + gx * (by + gy * bz);
    int sw = (id & 7) * (nwg >> 3) + (id >> 3);
    bx = sw % gx; int r2 = sw / gx;
    by = r2 % gy; bz = r2 / gy;
  }
  const int n0 = bx * BN, m0 = by * 256;
  const int NT = ((ncnt[bz] + 127) >> 7) << 1;

  const unsigned short* Ab = A + (size_t)bz * aStride;
  const unsigned short* Bb = Bm + (size_t)bz * bStride;

  const int lane = t & 63;
  const int w = t >> 6;
  const int wm = w >> 2, wn = w & 3;
  const int frow = lane & 15;
  const int kg8 = (lane >> 4) * 8;
  const int arow0 = (wm * 128 + frow) * 32;
  const int brow0 = (wn * (NJ * 16) + frow) * 32;

  const int srow = t >> 2;
  const int scol8 = (t & 3) * 8;
  const unsigned short* Asrc = Ab + (size_t)(m0 + srow) * lda + scol8;
  const unsigned short* Bsrc = Bb + (size_t)(n0 + srow) * ldb + scol8;
  const int sdst = w * 512;

  auto stgA = [&](int kt, int ks, int bufb) {
    const unsigned short* s = Asrc + kt * 64 + ks * 32;
    gload_lds16(s, &smem[bufb + ks * 8192 + sdst]);
    gload_lds16(s + (size_t)128 * lda, &smem[bufb + ks * 8192 + 4096 + sdst]);
  };
  auto stgB = [&](int kt, int ks, int bufb) {
    const unsigned short* s = Bsrc + kt * 64 + ks * 32;
    gload_lds16(s, &smem[bufb + 16384 + ks * 8192 + sdst]);
    gload_lds16(s + (size_t)128 * ldb, &smem[bufb + 16384 + ks * 8192 + 4096 + sdst]);
  };

  f32x4 acc[8][NJ] = {};
  bf16v8 aq[4], bq[NJ];

  stgA(0, 0, 0);     stgB(0, 0, 0);
  stgA(0, 1, 0);     stgB(0, 1, 0);
  stgA(1, 0, 32768); stgB(1, 0, 32768);
  asm volatile("s_waitcnt vmcnt(8)" ::: "memory");
  BARF;

  for (int ktp = 0; ktp < NT; ktp += 2) {
    TILEK(ktp, 0, 32768);
    TILEK(ktp + 1, 32768, 0);
  }

  const int r0 = (lane >> 4) * 4;
  const int c0 = lane & 15;
  const int mrowB = m0 + wm * 128 + r0;
  const int ncolB = n0 + wn * (NJ * 16) + c0;
  float* dst = Cf + (size_t)bz * cStride;
#pragma unroll
  for (int i = 0; i < 8; ++i)
#pragma unroll
    for (int j = 0; j < NJ; ++j)
#pragma unroll
      for (int r = 0; r < 4; ++r)
        dst[(size_t)(mrowB + i * 16 + r) * DD + (ncolB + j * 16)] = acc[i][j][r];
}

// ---- Merged Q + K/V projection, NJ=4, dense item pool, 2-pass coverage ----
// item < 192:  Q (64 m x 3 n): Q = Xb * Wcat[0:768]^T   (A contiguous)
// item >= 192: KV (GT x 6 n):  [Kc|Vtc] = gather(Xb,kidx) * Wcat[768:2304]^T
//   A staged with per-lane kidx indirection (independent base per 128-row half — r12 rule).
//   Pad rows map to kidx=0: garbage lands only in dead regions (softmax zeroes P there).
template <int NJ>
__global__ __launch_bounds__(512, 2) void gemmQKV(
    const unsigned short* __restrict__ Xb, const unsigned short* __restrict__ Wcat,
    unsigned short* __restrict__ Qb, unsigned short* __restrict__ Kc,
    unsigned short* __restrict__ Vtc,
    const int* __restrict__ kidx, const int* __restrict__ ncnt) {
  extern __shared__ unsigned short smem[];      // 131072 B
  constexpr int NT = 12;

  const int t = threadIdx.x;
  const int bid = (int)blockIdx.x;
  const int lid = (bid & 7) * 64 + (bid >> 3);   // XCD chunking (512 grid)

  const int lane = t & 63;
  const int w = t >> 6;
  const int wm = w >> 2, wn = w & 3;
  const int frow = lane & 15;
  const int kg8 = (lane >> 4) * 8;
  const int arow0 = (wm * 128 + frow) * 32;
  const int brow0 = (wn * (NJ * 16) + frow) * 32;
  const int srow = t >> 2;
  const int scol8 = (t & 3) * 8;
  const int sdst = w * 512;
  const int r0 = (lane >> 4) * 4;
  const int c0 = lane & 15;

  int offv[9]; offv[0] = 0;
#pragma unroll
  for (int i = 0; i < 8; ++i) offv[i + 1] = offv[i] + ((ncnt[i] + 255) & ~255);
  const int GT = offv[8] >> 8;
  const int nItems = 192 + GT * 6;

  f32x4 acc[8][NJ];
  bf16v8 aq[4], bq[NJ];

#pragma unroll 1
  for (int pass = 0; pass < 2; ++pass) {
    const int item = lid + pass * 512;
    if (item >= nItems) break;
    const bool isQ = item < 192;
    int m0 = 0, ncolQ = 0, b = 0, cbase0 = 0, ni = 0;
    const unsigned short *Asrc0, *Asrc1, *Bsrc;
    if (isQ) {
      m0 = (item / 3) * 256;
      ncolQ = (item % 3) * 256;
      Asrc0 = Xb + (size_t)(m0 + srow) * DD + scol8;
      Asrc1 = Asrc0 + (size_t)128 * DD;
      Bsrc  = Wcat + (size_t)(ncolQ + srow) * DD + scol8;
    } else {
      const int kid = item - 192;
      const int gt = kid / 6; ni = kid % 6;
#pragma unroll
      for (int i = 1; i < 8; ++i) if (offv[i] <= gt * 256) b = i;
      cbase0 = gt * 256 - offv[b];
      Asrc0 = Xb + ((size_t)b * NN + kidx[b * NN + cbase0 + srow]) * DD + scol8;
      Asrc1 = Xb + ((size_t)b * NN + kidx[b * NN + cbase0 + 128 + srow]) * DD + scol8;
      Bsrc  = Wcat + (size_t)(768 + ni * 256 + srow) * DD + scol8;
    }

    auto stgA = [&](int kt, int ks, int bufb) {
      gload_lds16(Asrc0 + kt * 64 + ks * 32, &smem[bufb + ks * 8192 + sdst]);
      gload_lds16(Asrc1 + kt * 64 + ks * 32, &smem[bufb + ks * 8192 + 4096 + sdst]);
    };
    auto stgB = [&](int kt, int ks, int bufb) {
      const unsigned short* s = Bsrc + kt * 64 + ks * 32;
      gload_lds16(s, &smem[bufb + 16384 + ks * 8192 + sdst]);
      gload_lds16(s + (size_t)128 * DD, &smem[bufb + 16384 + ks * 8192 + 4096 + sdst]);
    };

#pragma unroll
    for (int i = 0; i < 8; ++i)
#pragma unroll
      for (int j = 0; j < NJ; ++j) acc[i][j] = f32x4{0.f, 0.f, 0.f, 0.f};

    // prologue: vmcnt(8) also drains the previous pass's epilogue stores
    stgA(0, 0, 0);     stgB(0, 0, 0);
    stgA(0, 1, 0);     stgB(0, 1, 0);
    stgA(1, 0, 32768); stgB(1, 0, 32768);
    asm volatile("s_waitcnt vmcnt(8)" ::: "memory");
    BARF;

    for (int ktp = 0; ktp < NT; ktp += 2) {
      TILEK(ktp, 0, 32768);
      TILEK(ktp + 1, 32768, 0);
    }

    if (isQ) {
      const int mrowB = m0 + wm * 128 + r0;
      const int ncolB = ncolQ + wn * (NJ * 16) + c0;
#pragma unroll
      for (int i = 0; i < 8; ++i)
#pragma unroll
        for (int j = 0; j < NJ; ++j)
#pragma unroll
          for (int r = 0; r < 4; ++r)
            Qb[(size_t)(mrowB + i * 16 + r) * DD + (ncolB + j * 16)] = f2b(acc[i][j][r]);
    } else {
      const int rowL = wm * 128 + r0;
      const int ncolL = ni * 256 + wn * (NJ * 16) + c0;
      const int cbase = cbase0 + rowL;
      if (ni < 3) {   // K region: dense compacted rows, ld=768
        unsigned short* dst = Kc + (size_t)b * NN * DD;
#pragma unroll
        for (int i = 0; i < 8; ++i)
#pragma unroll
          for (int j = 0; j < NJ; ++j)
#pragma unroll
            for (int r = 0; r < 4; ++r)
              dst[(size_t)(cbase + i * 16 + r) * DD + (ncolL + j * 16)] = f2b(acc[i][j][r]);
      } else {        // V region (ncolL >= 768): transposed, dense compacted cols
#pragma unroll
        for (int i = 0; i < 8; ++i) {
#pragma unroll
          for (int j = 0; j < NJ; ++j) {
            const int e = ncolL + j * 16 - 768;
            ushort4v pk;
#pragma unroll
            for (int r = 0; r < 4; ++r) pk[r] = f2b(acc[i][j][r]);
            *(ushort4v*)&Vtc[((size_t)b * DD + e) * NN + cbase + i * 16] = pk;
          }
        }
      }
    }
  }
}

// ---- Persistent scores GEMM, 128x256 items: S[b][m][c] = Q[b][m] . Kc[b][c] ----
// Strided item map (r17): rem = bid + it*256 -> 3-round makespan at ~576 items.
__global__ __launch_bounds__(512, 2) void gemm1P(
    const unsigned short* __restrict__ Qa, const unsigned short* __restrict__ Kn,
    unsigned short* __restrict__ So, const int* __restrict__ ncnt) {
  extern __shared__ unsigned short smem[];      // 49152 elems = 98304 B
  constexpr int NT = 12;

  const int t = threadIdx.x;
  const int lane = t & 63;
  const int w = t >> 6;
  const int wm = w >> 2, wn = w & 3;
  const int frow = lane & 15;
  const int kg8 = (lane >> 4) * 8;
  const int arow0 = (wm * 64 + frow) * 32;
  const int brow0 = (wn * 64 + frow) * 32;
  const int srow = t >> 2;
  const int scol8 = (t & 3) * 8;
  const int sdst = w * 512;
  const int r0 = (lane >> 4) * 4;
  const int c0 = lane & 15;

  int nbv[8];
#pragma unroll
  for (int b_ = 0; b_ < 8; ++b_) nbv[b_] = (ncnt[b_] + 255) >> 8;

  f32x4 acc[4][4];
  bf16v8 aq[4], bq[4];

#pragma unroll 1
  for (int it = 0; it < 4; ++it) {
    int rem = (int)blockIdx.x + it * 256;
    int b = 0;
#pragma unroll 1
    for (; b < 8; ++b) { int c = nbv[b] * 16; if (rem < c) break; rem -= c; }
    if (b >= 8) break;
    const int ni = rem >> 4, mi = rem & 15;
    const int m0 = mi * 128, n0 = ni * 256;

    const unsigned short* Asrc = Qa + ((size_t)b * NN + m0 + srow) * DD + scol8;
    const unsigned short* Bsrc = Kn + ((size_t)b * NN + n0 + srow) * DD + scol8;

    auto stgA = [&](int kt, int ks, int bufb) {
      gload_lds16(Asrc + kt * 64 + ks * 32, &smem[bufb + ks * 4096 + sdst]);
    };
    auto stgB = [&](int kt, int ks, int bufb) {
      const unsigned short* s = Bsrc + kt * 64 + ks * 32;
      gload_lds16(s, &smem[bufb + 8192 + ks * 8192 + sdst]);
      gload_lds16(s + (size_t)128 * DD, &smem[bufb + 8192 + ks * 8192 + 4096 + sdst]);
    };

#pragma unroll
    for (int i = 0; i < 4; ++i)
#pragma unroll
      for (int j = 0; j < 4; ++j) acc[i][j] = f32x4{0.f, 0.f, 0.f, 0.f};

    stgA(0, 0, 0);     stgB(0, 0, 0);
    stgA(0, 1, 0);     stgB(0, 1, 0);
    stgA(1, 0, 24576); stgB(1, 0, 24576);
    VMC3;
    BARF;

#pragma unroll 1
    for (int kt = 0; kt < NT; ++kt) {
      const int cur = (kt & 1) ? 24576 : 0;
      const int nxt = cur ^ 24576;
#pragma unroll
      for (int i_ = 0; i_ < 4; ++i_)
        aq[i_] = *(const bf16v8*)&smem[cur + arow0 + i_ * 512 + kg8];
#pragma unroll
      for (int j_ = 0; j_ < 4; ++j_)
        bq[j_] = *(const bf16v8*)&smem[cur + 8192 + brow0 + j_ * 512 + kg8];
      if (kt + 1 < NT) { stgA(kt + 1, 1, nxt); stgB(kt + 1, 1, nxt); }
      BARF; P1;
#pragma unroll
      for (int i_ = 0; i_ < 4; ++i_)
#pragma unroll
        for (int j_ = 0; j_ < 4; ++j_)
          acc[i_][j_] = __builtin_amdgcn_mfma_f32_16x16x32_bf16(aq[i_], bq[j_], acc[i_][j_], 0, 0, 0);
      P0; BARF;
#pragma unroll
      for (int i_ = 0; i_ < 4; ++i_)
        aq[i_] = *(const bf16v8*)&smem[cur + 4096 + arow0 + i_ * 512 + kg8];
#pragma unroll
      for (int j_ = 0; j_ < 4; ++j_)
        bq[j_] = *(const bf16v8*)&smem[cur + 16384 + brow0 + j_ * 512 + kg8];
      if (kt + 2 < NT) { stgA(kt + 2, 0, cur); stgB(kt + 2, 0, cur); }
      BARF; P1;
#pragma unroll
      for (int i_ = 0; i_ < 4; ++i_)
#pragma unroll
        for (int j_ = 0; j_ < 4; ++j_)
          acc[i_][j_] = __builtin_amdgcn_mfma_f32_16x16x32_bf16(aq[i_], bq[j_], acc[i_][j_], 0, 0, 0);
      P0;
      if (kt < NT - 2) { VMC3; } else { VMC0; }
      BARF;
    }

    unsigned short* dst = So + (size_t)b * NN * NN;
    const int mrowB = m0 + wm * 64 + r0;
    const int ncolB = n0 + wn * 64 + c0;
#pragma unroll
    for (int i = 0; i < 4; ++i)
#pragma unroll
      for (int j = 0; j < 4; ++j)
#pragma unroll
        for (int r = 0; r < 4; ++r)
          dst[(size_t)(mrowB + i * 16 + r) * NN + (ncolB + j * 16)] = f2b(acc[i][j][r]);
  }
}

// ---------------- compacted softmax: cols [0,nc) valid, zero-fill [nc,r128), skip rest ----------------
__global__ __launch_bounds__(256) void softmax_c(unsigned short* __restrict__ S,
                                                 const int* __restrict__ ncnt) {
  int row = blockIdx.x;            // 0..16383
  int bb = row >> 11;
  const int nc = ncnt[bb];
  const int p128 = (nc + 127) & ~127;
  unsigned short* sr = S + (size_t)row * NN;
  int t = threadIdx.x;
  const int cbase = t * 8;

  float v[8];
  const bool anyload = cbase < nc;
  ushort8v pk;
  if (anyload) pk = *(const ushort8v*)&sr[cbase];
  float mx = -1e30f;
#pragma unroll
  for (int j = 0; j < 8; ++j) {
    v[j] = anyload ? b2f(pk[j]) : 0.f;
    if (cbase + j < nc) mx = fmaxf(mx, v[j]);
  }
  for (int o = 32; o > 0; o >>= 1) mx = fmaxf(mx, __shfl_xor(mx, o));
  __shared__ float redm[4], reds[4];
  int w = t >> 6, lane = t & 63;
  if (lane == 0) redm[w] = mx;
  __syncthreads();
  mx = fmaxf(fmaxf(redm[0], redm[1]), fmaxf(redm[2], redm[3]));

  float e[8];
  float sum = 0.f;
#pragma unroll
  for (int j = 0; j < 8; ++j) {
    e[j] = (cbase + j < nc) ? __expf(v[j] - mx) : 0.f;
    sum += e[j];
  }
  for (int o = 32; o > 0; o >>= 1) sum += __shfl_xor(sum, o);
  if (lane == 0) reds[w] = sum;
  __syncthreads();
  sum = reds[0] + reds[1] + reds[2] + reds[3];
  float inv = 1.0f / sum;

  if (cbase < p128) {
    ushort8v op;
#pragma unroll
    for (int j = 0; j < 8; ++j) op[j] = f2b(e[j] * inv);
    *(ushort8v*)&sr[cbase] = op;
  }
}

extern "C" void kernel_launch(void* const* d_in, const int* in_sizes, int n_in,
                              void* d_out, int out_size, void* d_ws, size_t ws_size,
                              hipStream_t stream) {
  const float* features = (const float*)d_in[0];
  const int* mask       = (const int*)d_in[1];
  const float* Wq       = (const float*)d_in[2];
  const float* Wk       = (const float*)d_in[3];
  const float* Wv       = (const float*)d_in[4];
  const float* gamma    = (const float*)d_in[5];
  const float* beta     = (const float*)d_in[6];
  float* out = (float*)d_out;

  char* ws = (char*)d_ws;
  size_t off = 0;
  auto alloc = [&](size_t bytes) {
    char* p = ws + off;
    off += (bytes + 255) & ~(size_t)255;
    return p;
  };
  unsigned short* Wcat = (unsigned short*)alloc((size_t)(2304 + 64) * DD * 2);
  unsigned short* Qb   = (unsigned short*)alloc((size_t)BB * NN * DD * 2);
  unsigned short* Kc   = (unsigned short*)alloc((size_t)BB * NN * DD * 2);   // compacted K rows
  unsigned short* Vtc  = (unsigned short*)alloc(((size_t)BB * DD + 64) * NN * 2);  // compacted Vt cols
  int* kidx = (int*)alloc((size_t)BB * NN * 4);
  int* ncnt = (int*)alloc(64 * 4);
  // S (67 MB): Xb aliases its first 25 MB (dead before gemm1P writes S).
  char* last = alloc((size_t)BB * NN * NN * 2);
  unsigned short* Sb = (unsigned short*)last;
  unsigned short* Xb = (unsigned short*)last;

  (void)hipFuncSetAttribute(reinterpret_cast<const void*>(&gemmQKV<4>),
                            hipFuncAttributeMaxDynamicSharedMemorySize, 131072);
  (void)hipFuncSetAttribute(reinterpret_cast<const void*>(&gemm1P),
                            hipFuncAttributeMaxDynamicSharedMemorySize, 98304);
  (void)hipFuncSetAttribute(reinterpret_cast<const void*>(&gemmCtx<3>),
                            hipFuncAttributeMaxDynamicSharedMemorySize, 131072);

  // 1) prep: LN ∪ Wconvert ∪ mask_scan
  prep<<<BB * NN + 6912 + BB, 256, 0, stream>>>(
      features, gamma, beta, Xb, Wq, Wk, Wv, Wcat, mask, kidx, ncnt);

  // 2) merged Q + K/V projection (KV stages A from Xb via kidx; no Xc materialization)
  gemmQKV<4><<<512, 512, 131072, stream>>>(Xb, Wcat, Qb, Kc, Vtc, kidx, ncnt);

  // 3) scores (dense compacted keys, strided 3-round item map)
  gemm1P<<<256, 512, 98304, stream>>>(Qb, Kc, Sb, ncnt);

  // 4) compacted softmax
  softmax_c<<<BB * NN, 256, 0, stream>>>(Sb, ncnt);

  // 5) context: per batch P[2048,r128] x Vtc[768,r128]^T -> f32 out
  gemmCtx<3><<<dim3(DD / 192, NN / 256, BB), 512, 131072, stream>>>(
      Sb, Vtc, out, NN, NN,
      (long)NN * NN, (long)DD * NN, (long)NN * DD, ncnt);
}